// Round 11
// baseline (314.801 us; speedup 1.0000x reference)
//
#include <hip/hip_runtime.h>
#include <hip/hip_bf16.h>
#include <math.h>

// Problem geometry (fixed by reference):
//   x: [B=16, C=256, 128, 128] fp32 ; H = 16 ; spatial N = 16384
#define BATCH 16
#define CH    256
#define HID   16
#define SPAT  16384            // 128*128
#define NPLANE (BATCH * CH)    // 4096 planes

typedef float vfloat4 __attribute__((ext_vector_type(4)));

// ---------------------------------------------------------------------------
// Kernel 1: per-(b,c) spatial mean & biased std. One block per plane.
// Cached forward loads (leaves the tail of x resident in L3 for kernel 2's
// reverse-order re-read). This is the R3 kernel unchanged (proven 148 µs path).
// ---------------------------------------------------------------------------
__global__ __launch_bounds__(256) void stats_kernel(const float* __restrict__ x,
                                                    float* __restrict__ mean_g,
                                                    float* __restrict__ std_g)
{
    const long long base = (long long)blockIdx.x * SPAT;
    const vfloat4* x4 = reinterpret_cast<const vfloat4*>(x + base);

    float s = 0.f, s2 = 0.f;
    #pragma unroll
    for (int i = 0; i < 16; ++i) {
        vfloat4 v = x4[threadIdx.x + i * 256];
        s  += v.x + v.y + v.z + v.w;
        s2 += v.x * v.x + v.y * v.y + v.z * v.z + v.w * v.w;
    }

    #pragma unroll
    for (int off = 32; off > 0; off >>= 1) {
        s  += __shfl_xor(s,  off);
        s2 += __shfl_xor(s2, off);
    }

    __shared__ float ws[4], ws2[4];
    const int wave = threadIdx.x >> 6;
    const int lane = threadIdx.x & 63;
    if (lane == 0) { ws[wave] = s; ws2[wave] = s2; }
    __syncthreads();

    if (threadIdx.x == 0) {
        const float ts  = ws[0]  + ws[1]  + ws[2]  + ws[3];
        const float ts2 = ws2[0] + ws2[1] + ws2[2] + ws2[3];
        const float m   = ts * (1.f / SPAT);
        const float var = ts2 * (1.f / SPAT) - m * m;
        mean_g[blockIdx.x] = m;
        std_g[blockIdx.x]  = sqrtf(fmaxf(var, 0.f));
    }
}

// ---------------------------------------------------------------------------
// Kernel 2: fused SE-chain + scale. One block per plane (reverse order).
// Each block redundantly computes the full SE chain for its batch row
// (~150K FLOP, weights are L2-resident broadcast reads), takes its own
// channel's sigmoid, then streams out = x * m with NT stores.
// ---------------------------------------------------------------------------
__global__ __launch_bounds__(256) void scale_fused_kernel(
    const float* __restrict__ x,
    const float* __restrict__ mean_g, const float* __restrict__ std_g,
    const float* __restrict__ sw1, const float* __restrict__ sb1,
    const float* __restrict__ sw2, const float* __restrict__ sb2,
    const float* __restrict__ mw1, const float* __restrict__ mb1,
    const float* __restrict__ mw2, const float* __restrict__ mb2,
    const float* __restrict__ bw,  const float* __restrict__ bb,
    const float* __restrict__ fw1, const float* __restrict__ fb1,
    const float* __restrict__ fw2, const float* __restrict__ fb2,
    float* __restrict__ out)
{
    const int plane = (NPLANE - 1) - blockIdx.x;   // reverse order (L3 tail-hot)
    const int brow  = plane >> 8;                  // batch row
    const int mych  = plane & 255;                 // this block's channel
    const int tid   = threadIdx.x;

    __shared__ float s_desc[2 * CH];   // [std | mean]
    __shared__ float s_h[HID];
    __shared__ float s_fused[2 * CH];
    __shared__ float s_g[CH];
    __shared__ float s_mval;

    s_desc[tid]      = std_g [brow * CH + tid];
    s_desc[CH + tid] = mean_g[brow * CH + tid];
    __syncthreads();

    auto se_l1 = [&](const float* desc, const float* __restrict__ w1,
                     const float* __restrict__ b1) {
        const int hh = tid >> 4;
        const int j  = tid & 15;
        float acc = 0.f;
        #pragma unroll
        for (int k = 0; k < 16; ++k) {
            const int c = j * 16 + k;
            acc += desc[c] * w1[hh * CH + c];
        }
        #pragma unroll
        for (int off = 1; off < 16; off <<= 1)
            acc += __shfl_xor(acc, off, 16);
        if (j == 0) s_h[hh] = fmaxf(acc + b1[hh], 0.f);
    };
    auto se_l2 = [&](const float* __restrict__ w2, const float* __restrict__ b2,
                     float* outbuf) {
        float acc = b2[tid];
        const vfloat4* w4 = reinterpret_cast<const vfloat4*>(w2 + tid * HID);
        #pragma unroll
        for (int q = 0; q < 4; ++q) {
            const vfloat4 wv = w4[q];
            acc += s_h[q * 4 + 0] * wv.x + s_h[q * 4 + 1] * wv.y
                 + s_h[q * 4 + 2] * wv.z + s_h[q * 4 + 3] * wv.w;
        }
        outbuf[tid] = acc;
    };

    se_l1(s_desc, sw1, sb1);
    __syncthreads();
    se_l2(sw2, sb2, s_fused);
    __syncthreads();
    se_l1(s_desc + CH, mw1, mb1);
    __syncthreads();
    se_l2(mw2, mb2, s_fused + CH);
    __syncthreads();

    {   // bottleneck: g[c] = relu(fused . bw[c,:] + bb[c])
        float acc = bb[tid];
        const vfloat4* wrow = reinterpret_cast<const vfloat4*>(bw + tid * (2 * CH));
        const vfloat4* f4   = reinterpret_cast<const vfloat4*>(s_fused);
        #pragma unroll 8
        for (int q = 0; q < (2 * CH) / 4; ++q) {
            const vfloat4 wv = wrow[q];
            const vfloat4 fv = f4[q];
            acc += fv.x * wv.x + fv.y * wv.y + fv.z * wv.z + fv.w * wv.w;
        }
        s_g[tid] = fmaxf(acc, 0.f);
    }
    __syncthreads();

    se_l1(s_g, fw1, fb1);
    __syncthreads();
    {
        float acc = fb2[tid];
        const vfloat4* w4 = reinterpret_cast<const vfloat4*>(fw2 + tid * HID);
        #pragma unroll
        for (int q = 0; q < 4; ++q) {
            const vfloat4 wv = w4[q];
            acc += s_h[q * 4 + 0] * wv.x + s_h[q * 4 + 1] * wv.y
                 + s_h[q * 4 + 2] * wv.z + s_h[q * 4 + 3] * wv.w;
        }
        if (tid == mych)
            s_mval = 1.f / (1.f + expf(-acc));
    }
    __syncthreads();

    // ---- streaming scale: out[plane] = x[plane] * m, NT stores ----
    const float m = s_mval;
    const long long base = (long long)plane * SPAT;
    const vfloat4* x4 = reinterpret_cast<const vfloat4*>(x + base);
    vfloat4*       o4 = reinterpret_cast<vfloat4*>(out + base);
    #pragma unroll
    for (int i = 0; i < 16; ++i) {
        vfloat4 v = x4[tid + i * 256];
        v *= m;
        __builtin_nontemporal_store(v, &o4[tid + i * 256]);
    }
}

// ---------------------------------------------------------------------------
extern "C" void kernel_launch(void* const* d_in, const int* in_sizes, int n_in,
                              void* d_out, int out_size, void* d_ws, size_t ws_size,
                              hipStream_t stream)
{
    const float* x   = (const float*)d_in[0];
    const float* sw1 = (const float*)d_in[1];
    const float* sb1 = (const float*)d_in[2];
    const float* sw2 = (const float*)d_in[3];
    const float* sb2 = (const float*)d_in[4];
    const float* mw1 = (const float*)d_in[5];
    const float* mb1 = (const float*)d_in[6];
    const float* mw2 = (const float*)d_in[7];
    const float* mb2 = (const float*)d_in[8];
    const float* bw  = (const float*)d_in[9];
    const float* bb  = (const float*)d_in[10];
    const float* fw1 = (const float*)d_in[11];
    const float* fb1 = (const float*)d_in[12];
    const float* fw2 = (const float*)d_in[13];
    const float* fb2 = (const float*)d_in[14];

    float* out = (float*)d_out;

    float* mean_g = (float*)d_ws;
    float* std_g  = mean_g + NPLANE;

    stats_kernel<<<NPLANE, 256, 0, stream>>>(x, mean_g, std_g);
    scale_fused_kernel<<<NPLANE, 256, 0, stream>>>(x, mean_g, std_g,
                                                   sw1, sb1, sw2, sb2,
                                                   mw1, mb1, mw2, mb2,
                                                   bw, bb,
                                                   fw1, fb1, fw2, fb2,
                                                   out);
}